// Round 11
// baseline (226.701 us; speedup 1.0000x reference)
//
#include <hip/hip_runtime.h>
#include <stdint.h>

typedef __attribute__((ext_vector_type(8))) short short8;   // 8 bf16 (4 VGPRs)
typedef __attribute__((ext_vector_type(4))) short short4b;  // 4 bf16 (2 VGPRs)
typedef __attribute__((ext_vector_type(4))) float f32x4;    // MFMA acc

#define MFMA16(a, b, c) __builtin_amdgcn_mfma_f32_16x16x32_bf16((a), (b), (c), 0, 0, 0)

#if defined(__HIP_DEVICE_COMPILE__)
  #if __has_builtin(__builtin_amdgcn_mfma_f32_16x16x16bf16_1k)
    #define MFMA16K16(a, b, c) __builtin_amdgcn_mfma_f32_16x16x16bf16_1k((a), (b), (c), 0, 0, 0)
  #else
    #define MFMA16K16(a, b, c) __builtin_amdgcn_mfma_f32_16x16x16_bf16((a), (b), (c), 0, 0, 0)
  #endif
  #if __has_builtin(__builtin_amdgcn_exp2f)
    #define EXP2(x) __builtin_amdgcn_exp2f(x)   // raw v_exp_f32: 1 instr, exact for our S>=0 range
  #else
    #define EXP2(x) exp2f(x)
  #endif
#else
  #define MFMA16K16(a, b, c) (c)
  #define EXP2(x) exp2f(x)
#endif

#define SCL_F (0.125f * 1.44269504f)   // dk^-0.5 folded with log2(e)

__device__ __forceinline__ float b2f(unsigned short u) {
    union { unsigned u; float f; } c; c.u = ((unsigned)u) << 16; return c.f;
}
__device__ __forceinline__ unsigned short f2b(float f) {
    union { float f; unsigned u; } c; c.f = f;
    unsigned r = c.u + 0x7FFF + ((c.u >> 16) & 1);   // round-to-nearest-even
    return (unsigned short)(r >> 16);
}
__device__ __forceinline__ unsigned f_as_u(float f) {
    union { float f; unsigned u; } c; c.f = f; return c.u;
}
__device__ __forceinline__ short8 cvt8(float4 a, float4 b) {
    union { short8 v; unsigned short u[8]; } o;
    o.u[0] = f2b(a.x); o.u[1] = f2b(a.y); o.u[2] = f2b(a.z); o.u[3] = f2b(a.w);
    o.u[4] = f2b(b.x); o.u[5] = f2b(b.y); o.u[6] = f2b(b.z); o.u[7] = f2b(b.w);
    return o.v;
}

// async global->LDS, 16B per lane; LDS dest = wave-uniform base + lane*16.
__device__ __forceinline__ void g2lds16(const void* g, unsigned lds_byte_off) {
    __builtin_amdgcn_global_load_lds(
        (const __attribute__((address_space(1))) void*)(uintptr_t)g,
        (__attribute__((address_space(3))) void*)(uintptr_t)lds_byte_off,
        16, 0, 0);
}

// ---------------------------------------------------------------------------
// Dtype canary (proven): flag=1 => f32 inputs, 0 => bf16.
// ---------------------------------------------------------------------------
__global__ void detect_dtype(const unsigned short* __restrict__ x, int* __restrict__ flag) {
    __shared__ int cnt;
    if (threadIdx.x == 0) cnt = 0;
    __syncthreads();
    int insane = 0;
    #pragma unroll
    for (int j = 0; j < 4; ++j) {
        unsigned short u = x[threadIdx.x * 4 + j];
        int e = (u >> 7) & 0xFF;
        if ((e >= 1 && e <= 90) || e >= 165) insane++;
    }
    atomicAdd(&cnt, insane);
    __syncthreads();
    if (threadIdx.x == 0) *flag = (cnt > 128) ? 1 : 0;
}

// ---------------------------------------------------------------------------
// Weight convert+transpose (z=0..3) and biases (z=4). Round-23: x-conversion
// slices REMOVED — gemm_qkv now reads f32 x directly (fused conversion).
// Wq (z=0) and bq (w=0) are SCALED by SCL_F.
// ---------------------------------------------------------------------------
__global__ __launch_bounds__(256) void convtrans_k(const void* __restrict__ s0, const void* __restrict__ s1,
                                                   const void* __restrict__ s2, const void* __restrict__ s3,
                                                   const void* __restrict__ b0, const void* __restrict__ b1,
                                                   const void* __restrict__ b2, const void* __restrict__ b3s,
                                                   unsigned short* __restrict__ dstBase,
                                                   unsigned short* __restrict__ dstB3,
                                                   unsigned short* __restrict__ dstBo,
                                                   const int* __restrict__ flag) {
    const int z = blockIdx.z;
    if (z == 4) {           // biases (bq scaled by SCL_F)
        if (blockIdx.y != 0 || blockIdx.x >= 4) return;
        const int w = blockIdx.x;
        const void* src = (w == 0) ? b0 : (w == 1) ? b1 : (w == 2) ? b2 : b3s;
        const float bscl = (w == 0) ? SCL_F : 1.0f;
        #pragma unroll
        for (int j = 0; j < 4; ++j) {
            const int i = threadIdx.x * 4 + j;
            float fv = (*flag) ? ((const float*)src)[i] : b2f(((const unsigned short*)src)[i]);
            unsigned short v = f2b(fv * bscl);
            if (w < 3) dstB3[w * 1024 + i] = v;
            else dstBo[i] = v;
        }
        return;
    }
    __shared__ __align__(16) unsigned short tile[64 * 72];
    const void* src = (z == 0) ? s0 : (z == 1) ? s1 : (z == 2) ? s2 : s3;
    unsigned short* dst = dstBase + (size_t)z * 1024 * 1024;
    const float wscl = (z == 0) ? SCL_F : 1.0f;
    const int tid = threadIdx.x;
    const int r0 = blockIdx.y * 64, c0 = blockIdx.x * 64;
    const int rb = tid >> 3, c = (tid & 7) * 8;
    if (*flag) {
        const float* s = (const float*)src;
        #pragma unroll
        for (int it = 0; it < 2; ++it) {
            int rr = it * 32 + rb;
            float4 f0 = *(const float4*)&s[(size_t)(r0 + rr) * 1024 + c0 + c];
            float4 f1 = *(const float4*)&s[(size_t)(r0 + rr) * 1024 + c0 + c + 4];
            unsigned short* t = &tile[rr * 72 + c];
            t[0] = f2b(f0.x * wscl); t[1] = f2b(f0.y * wscl); t[2] = f2b(f0.z * wscl); t[3] = f2b(f0.w * wscl);
            t[4] = f2b(f1.x * wscl); t[5] = f2b(f1.y * wscl); t[6] = f2b(f1.z * wscl); t[7] = f2b(f1.w * wscl);
        }
    } else if (z == 0) {
        const unsigned short* s = (const unsigned short*)src;
        #pragma unroll
        for (int it = 0; it < 2; ++it) {
            int rr = it * 32 + rb;
            union { short8 v; unsigned short u[8]; } in;
            in.v = *(const short8*)&s[(size_t)(r0 + rr) * 1024 + c0 + c];
            unsigned short* t = &tile[rr * 72 + c];
            #pragma unroll
            for (int j = 0; j < 8; ++j) t[j] = f2b(b2f(in.u[j]) * SCL_F);
        }
    } else {
        const unsigned short* s = (const unsigned short*)src;
        #pragma unroll
        for (int it = 0; it < 2; ++it) {
            int rr = it * 32 + rb;
            *(short8*)&tile[rr * 72 + c] = *(const short8*)&s[(size_t)(r0 + rr) * 1024 + c0 + c];
        }
    }
    __syncthreads();
    #pragma unroll
    for (int it = 0; it < 2; ++it) {
        int n = it * 32 + rb, k8 = c;
        union { short8 s; unsigned short u[8]; } tmp;
        #pragma unroll
        for (int j = 0; j < 8; ++j) tmp.u[j] = tile[(k8 + j) * 72 + n];
        *(short8*)&dst[(size_t)(c0 + n) * 1024 + r0 + k8] = tmp.s;
    }
}

// ---------------------------------------------------------------------------
// QKV GEMM, Round-23: reads x DIRECTLY (f32 when flag=1 — fused conversion;
// bf16 when flag=0). BM=BN=128, BK=32, 3-deep counted-vmcnt pipeline.
//   flag=1 path: A staged as f32 tiles [128][32]f32 (16KB each, 3 buffers)
//     via gload_lds with pre-swizzled source chunks c'=(l&7)^(l>>3); frag
//     reads at chunk (2q+j)^(row&7) -> uniform 2-way banks (free, m136);
//     f2b conversion at read time (bit-identical to old convtrans output).
//     6 loads/tile (4 A + 2 B) -> vmcnt(12)/6/0. LDS 72KB (2 blocks/CU).
//   flag=0 path: R9's bf16 path (T2-swizzled A/B, 4 loads/tile, vmcnt 8/4/0).
// LDS-bounce epilogue with fused mask (R8) unchanged.
// ---------------------------------------------------------------------------
__global__ __launch_bounds__(256) void gemm_qkv(const void* __restrict__ Araw,
                                                const unsigned short* __restrict__ BT,
                                                const unsigned short* __restrict__ bias,
                                                unsigned short* __restrict__ qkv,
                                                unsigned short* __restrict__ VtG,
                                                const int* __restrict__ mask,
                                                const int* __restrict__ flag,
                                                int K) {
    __shared__ __align__(16) unsigned short smem[36864];   // 72KB; epilogue reuses
    const int tid = threadIdx.x;
    const int wave = tid >> 6, lane = tid & 63;
    const int quad = lane >> 4, l16 = lane & 15;
    const int wm = wave >> 1, wn = wave & 1;
    const int m0 = blockIdx.y * 128, n0 = blockIdx.x * 128;

    f32x4 acc[4][4];
    #pragma unroll
    for (int i = 0; i < 4; i++)
        #pragma unroll
        for (int j = 0; j < 4; j++) acc[i][j] = (f32x4){0.f, 0.f, 0.f, 0.f};

    // B staging geometry (T2 pre-swizzle, R9) — shared by both paths
    const int r2 = lane >> 3, sl = lane & 7;
    const int sp = sl ^ r2;
    const int rowl = r2 * 2 + (sp >> 2);
    const int col8 = (sp & 3) * 8;
    const unsigned short* gB0 = BT + (size_t)(n0 + wave * 32 + rowl) * K + col8;
    const unsigned short* gB1 = gB0 + (size_t)16 * K;
    // B read geometry (T2)
    const int swz = (((l16 & 1) << 2) | quad) ^ (l16 >> 1);
    const int hp  = l16 >> 1;

    if (*flag) {
        // ------------------- f32-A path -------------------
        const float* Af = (const float*)Araw;
        const int ar  = lane >> 3;                   // row-in-8 within an op
        const int acg = (lane & 7) ^ ar;             // pre-swizzled 16B chunk
        const float* gAf = Af + (size_t)(m0 + wave * 32 + ar) * K + acg * 4;
        const size_t arow8 = (size_t)8 * K;          // 8-row stride (floats)

        // A: 3 x 16KB at 0/16384/32768; B: 3 x 8KB at 49152/57344/65536
        const unsigned base = (unsigned)(uintptr_t)&smem[0];
        unsigned fA0 = base + wave * 4096;
        unsigned fA1 = fA0 + 16384;
        unsigned fA2 = fA0 + 32768;
        unsigned fB0 = base + 49152 + wave * 2048;
        unsigned fB1 = fB0 + 8192;
        unsigned fB2 = fB0 + 16384;
        const char* qA0 = (const char*)&smem[0];
        const char* qA1 = qA0 + 16384;
        const char* qA2 = qA0 + 32768;
        const unsigned short* qB0 = (const unsigned short*)((const char*)&smem[0] + 49152);
        const unsigned short* qB1 = qB0 + 4096;
        const unsigned short* qB2 = qB0 + 8192;

        #define STAGE_F32(k0_, lA_, lB_) do {                                   \
            g2lds16(gAf + (k0_),              (lA_));                           \
            g2lds16(gAf + (k0_) + arow8,      (lA_) + 1024);                    \
            g2lds16(gAf + (k0_) + 2 * arow8,  (lA_) + 2048);                    \
            g2lds16(gAf + (k0_) + 3 * arow8,  (lA_) + 3072);                    \
            g2lds16(gB0 + (k0_), (lB_));                                        \
            g2lds16(gB1 + (k0_), (lB_) + 1024);                                 \
        } while (0)

        STAGE_F32(0, fA0, fB0);
        if (32 < K) STAGE_F32(32, fA1, fB1);
        if (64 < K) STAGE_F32(64, fA2, fB2);

        const int h8 = l16 & 7;
        for (int k0 = 0; k0 < K; k0 += 32) {
            if (k0 + 64 < K)       asm volatile("s_waitcnt vmcnt(12)" ::: "memory");
            else if (k0 + 32 < K)  asm volatile("s_waitcnt vmcnt(6)" ::: "memory");
            else                   asm volatile("s_waitcnt vmcnt(0)" ::: "memory");
            __builtin_amdgcn_s_barrier();

            short8 af[4], bf[4];
            #pragma unroll
            for (int i = 0; i < 4; i++) {
                const int row = wm * 64 + i * 16 + l16;
                const float4 a0 = *(const float4*)(qA0 + row * 128 + (((quad * 2 + 0) ^ h8) << 4));
                const float4 a1 = *(const float4*)(qA0 + row * 128 + (((quad * 2 + 1) ^ h8) << 4));
                af[i] = cvt8(a0, a1);
            }
            #pragma unroll
            for (int j = 0; j < 4; j++) bf[j] = *(const short8*)&qB0[(wn * 32 + j * 8 + hp) * 64 + swz * 8];
            #pragma unroll
            for (int i = 0; i < 4; i++)
                #pragma unroll
                for (int j = 0; j < 4; j++)
                    acc[i][j] = MFMA16(af[i], bf[j], acc[i][j]);

            __builtin_amdgcn_s_barrier();

            if (k0 + 96 < K) STAGE_F32(k0 + 96, fA0, fB0);
            unsigned tu;
            tu = fA0; fA0 = fA1; fA1 = fA2; fA2 = tu;
            tu = fB0; fB0 = fB1; fB1 = fB2; fB2 = tu;
            const char* tc;
            tc = qA0; qA0 = qA1; qA1 = qA2; qA2 = tc;
            const unsigned short* tp;
            tp = qB0; qB0 = qB1; qB1 = qB2; qB2 = tp;
        }
        #undef STAGE_F32
    } else {
        // ------------------- bf16-A path (R9, unchanged) -------------------
        const unsigned short* Ab = (const unsigned short*)Araw;
        const unsigned short* gA0 = Ab + (size_t)(m0 + wave * 32 + rowl) * K + col8;
        const unsigned short* gA1 = gA0 + (size_t)16 * K;

        const unsigned sA = (unsigned)(uintptr_t)&smem[0];
        const unsigned sB = sA + 24576;
        unsigned lA0 = sA + wave * 2048;
        unsigned lA1 = sA + 8192 + wave * 2048;
        unsigned lA2 = sA + 16384 + wave * 2048;
        unsigned lB0 = sB + wave * 2048;
        unsigned lB1 = sB + 8192 + wave * 2048;
        unsigned lB2 = sB + 16384 + wave * 2048;
        const unsigned short* pA0 = &smem[0];
        const unsigned short* pA1 = &smem[4096];
        const unsigned short* pA2 = &smem[8192];
        const unsigned short* pB0 = &smem[12288];
        const unsigned short* pB1 = &smem[16384];
        const unsigned short* pB2 = &smem[20480];

        g2lds16(gA0, lA0); g2lds16(gA1, lA0 + 1024);
        g2lds16(gB0, lB0); g2lds16(gB1, lB0 + 1024);
        if (32 < K) {
            g2lds16(gA0 + 32, lA1); g2lds16(gA1 + 32, lA1 + 1024);
            g2lds16(gB0 + 32, lB1); g2lds16(gB1 + 32, lB1 + 1024);
        }
        if (64 < K) {
            g2lds16(gA0 + 64, lA2); g2lds16(gA1 + 64, lA2 + 1024);
            g2lds16(gB0 + 64, lB2); g2lds16(gB1 + 64, lB2 + 1024);
        }

        for (int k0 = 0; k0 < K; k0 += 32) {
            if (k0 + 64 < K)       asm volatile("s_waitcnt vmcnt(8)" ::: "memory");
            else if (k0 + 32 < K)  asm volatile("s_waitcnt vmcnt(4)" ::: "memory");
            else                   asm volatile("s_waitcnt vmcnt(0)" ::: "memory");
            __builtin_amdgcn_s_barrier();

            short8 af[4], bf[4];
            #pragma unroll
            for (int i = 0; i < 4; i++) af[i] = *(const short8*)&pA0[(wm * 32 + i * 8 + hp) * 64 + swz * 8];
            #pragma unroll
            for (int j = 0; j < 4; j++) bf[j] = *(const short8*)&pB0[(wn * 32 + j * 8 + hp) * 64 + swz * 8];
            #pragma unroll
            for (int i = 0; i < 4; i++)
                #pragma unroll
                for (int j = 0; j < 4; j++)
                    acc[i][j] = MFMA16(af[i], bf[j], acc[i][j]);

            __builtin_amdgcn_s_barrier();

            if (k0 + 96 < K) {
                g2lds16(gA0 + k0 + 96, lA0); g2lds16(gA1 + k0 + 96, lA0 + 1024);
                g2lds16(gB0 + k0 + 96, lB0); g2lds16(gB1 + k0 + 96, lB0 + 1024);
            }
            unsigned tu;
            tu = lA0; lA0 = lA1; lA1 = lA2; lA2 = tu;
            tu = lB0; lB0 = lB1; lB1 = lB2; lB2 = tu;
            const unsigned short* tp;
            tp = pA0; pA0 = pA1; pA1 = pA2; pA2 = tp;
            tp = pB0; pB0 = pB1; pB1 = pB2; pB2 = tp;
        }
    }
    // last iter's second barrier has run: staging LDS free for epilogue reuse.

    unsigned short* epi = &smem[0];                 // 128 x (132) tile, 33.8KB
    if (n0 >= 2048) {
        // V: store transposed into LDS: epi[col_local*132 + row_local]
        #pragma unroll
        for (int j = 0; j < 4; j++) {
            const int cl = wn * 64 + j * 16 + l16;
            const float bj = b2f(bias[n0 + cl]);
            #pragma unroll
            for (int i = 0; i < 4; i++) {
                const int rl = wm * 64 + i * 16 + quad * 4;
                #pragma unroll
                for (int r = 0; r < 4; r++) {
                    float v = acc[i][j][r] + bj;
                    v = v > 0.f ? v : 0.f;
                    epi[cl * 132 + rl + r] = f2b(v);
                }
            }
        }
        __syncthreads();
        // coalesced store: thread t -> col t>>1, half (t&1)*64; 128B contiguous
        const int cl = tid >> 1, half = (tid & 1) * 64;
        const int colg = n0 + cl;
        const int h  = (colg - 2048) >> 6;
        const int dk = (colg - 2048) & 63;
        const int bb = m0 >> 11;
        unsigned short* dst = &VtG[((size_t)(bb * 16 + h) * 64 + dk) * 2048 + (m0 & 2047) + half];
        const unsigned short* src = &epi[cl * 132 + half];
        #pragma unroll
        for (int k = 0; k < 8; k++) *(short8*)&dst[k * 8] = *(const short8*)&src[k * 8];
    } else {
        // Q/K: store row-major into LDS: epi[row_local*132 + col_local]
        #pragma unroll
        for (int j = 0; j < 4; j++) {
            const int cl = wn * 64 + j * 16 + l16;
            const float bj = b2f(bias[n0 + cl]);
            #pragma unroll
            for (int i = 0; i < 4; i++) {
                const int rl = wm * 64 + i * 16 + quad * 4;
                #pragma unroll
                for (int r = 0; r < 4; r++) {
                    float v = acc[i][j][r] + bj;
                    v = v > 0.f ? v : 0.f;
                    epi[(rl + r) * 132 + cl] = f2b(v);
                }
            }
        }
        __syncthreads();
        const int row = tid >> 1, half = (tid & 1) * 64;
        const int rowg = m0 + row;
        const int mz = (n0 >= 1024) && mask[rowg];          // K third + masked row
        unsigned short* dst = &qkv[(size_t)rowg * 3072 + n0 + half];
        const unsigned short* src = &epi[row * 132 + half];
        const short8 zero = {0, 0, 0, 0, 0, 0, 0, 0};
        #pragma unroll
        for (int k = 0; k < 8; k++) *(short8*)&dst[k * 8] = mz ? zero : *(const short8*)&src[k * 8];
    }
}

// ---------------------------------------------------------------------------
// OUT projection (R9 form, best-total config): BM=64 x BN=128, BK=32,
// 3-deep pipeline + T2 swizzle. relu(A@BT^T+bias); f32 out when flag.
// ---------------------------------------------------------------------------
__global__ __launch_bounds__(256) void gemm64_bias_relu(const unsigned short* __restrict__ A,
                                                        const unsigned short* __restrict__ BT,
                                                        const unsigned short* __restrict__ bias,
                                                        void* __restrict__ C,
                                                        const int* __restrict__ flag,
                                                        int N, int K) {
    __shared__ __align__(16) unsigned short As[3][64 * 32];
    __shared__ __align__(16) unsigned short Bs[3][128 * 32];
    const int tid = threadIdx.x;
    const int wave = tid >> 6, lane = tid & 63;
    const int quad = lane >> 4, l16 = lane & 15;
    const int wm = wave >> 1, wn = wave & 1;      // wave tile: 32 rows x 64 cols
    const int m0 = blockIdx.y * 64, n0 = blockIdx.x * 128;

    f32x4 acc[2][4];
    #pragma unroll
    for (int i = 0; i < 2; i++)
        #pragma unroll
        for (int j = 0; j < 4; j++) acc[i][j] = (f32x4){0.f, 0.f, 0.f, 0.f};

    // T2 staging geometry
    const int r2 = lane >> 3, sl = lane & 7;
    const int sp = sl ^ r2;
    const int rowl = r2 * 2 + (sp >> 2);
    const int col8 = (sp & 3) * 8;
    const unsigned short* gA0 = A + (size_t)(m0 + wave * 16 + rowl) * K + col8;
    const unsigned short* gB0 = BT + (size_t)(n0 + wave * 32 + rowl) * K + col8;
    const unsigned short* gB1 = gB0 + (size_t)16 * K;

    unsigned lA0 = (unsigned)(uintptr_t)&As[0][0] + wave * 1024;
    unsigned lA1 = (unsigned)(uintptr_t)&As[1][0] + wave * 1024;
    unsigned lA2 = (unsigned)(uintptr_t)&As[2][0] + wave * 1024;
    unsigned lB0 = (unsigned)(uintptr_t)&Bs[0][0] + wave * 2048;
    unsigned lB1 = (unsigned)(uintptr_t)&Bs[1][0] + wave * 2048;
    unsigned lB2 = (unsigned)(uintptr_t)&Bs[2][0] + wave * 2048;
    const unsigned short* pA0 = &As[0][0];
    const unsigned short* pA1 = &As[1][0];
    const unsigned short* pA2 = &As[2][0];
    const unsigned short* pB0 = &Bs[0][0];
    const unsigned short* pB1 = &Bs[1][0];
    const unsigned short* pB2 = &Bs[2][0];

    const int swz = (((l16 & 1) << 2) | quad) ^ (l16 >> 1);
    const int hp  = l16 >> 1;

    g2lds16(gA0, lA0);
    g2lds16(gB0, lB0); g2lds16(gB1, lB0 + 1024);
    if (32 < K) {
        g2lds16(gA0 + 32, lA1);
        g2lds16(gB0 + 32, lB1); g2lds16(gB1 + 32, lB1 + 1024);
    }
    if (64 < K) {
        g2lds16(gA0 + 64, lA2);
        g2lds16(gB0 + 64, lB2); g2lds16(gB1 + 64, lB2 + 1024);
    }

    for (int k0 = 0; k0 < K; k0 += 32) {
        if (k0 + 64 < K)       asm volatile("s_waitcnt vmcnt(6)" ::: "memory");
        else if (k0 + 32 < K)  asm volatile("s_waitcnt vmcnt(3)" ::: "memory");
        else                   asm volatile("s_waitcnt vmcnt(0)" ::: "memory");
        __builtin_amdgcn_s_barrier();

        short8 af[2], bf[4];
        #pragma unroll
        for (int i = 0; i < 2; i++) af[i] = *(const short8*)&pA0[(wm * 16 + i * 8 + hp) * 64 + swz * 8];
        #pragma unroll
        for (int j = 0; j < 4; j++) bf[j] = *(const short8*)&pB0[(wn * 32 + j * 8 + hp) * 64 + swz * 8];
        #pragma unroll
        for (int i = 0; i < 2; i++)
            #pragma unroll
            for (int j = 0; j < 4; j++)
                acc[i][j] = MFMA16(af[i], bf[j], acc[i][j]);

        __builtin_amdgcn_s_barrier();

        if (k0 + 96 < K) {
            g2lds16(gA0 + k0 + 96, lA0);
            g2lds16(gB0 + k0 + 96, lB0); g2lds16(gB1 + k0 + 96, lB0 + 1024);
        }
        unsigned tu;
        tu = lA0; lA0 = lA1; lA1 = lA2; lA2 = tu;
        tu = lB0; lB0 = lB1; lB1 = lB2; lB2 = tu;
        const unsigned short* tp;
        tp = pA0; pA0 = pA1; pA1 = pA2; pA2 = tp;
        tp = pB0; pB0 = pB1; pB1 = pB2; pB2 = tp;
    }

    const int f32out = (*flag != 0);
    #pragma unroll
    for (int j = 0; j < 4; j++) {
        const int col = n0 + wn * 64 + j * 16 + l16;
        const float bj = b2f(bias[col]);
        #pragma unroll
        for (int i = 0; i < 2; i++) {
            const int rowb = m0 + wm * 32 + i * 16 + quad * 4;
            #pragma unroll
            for (int r = 0; r < 4; r++) {
                float v = acc[i][j][r] + bj;
                v = v > 0.f ? v : 0.f;
                if (f32out) ((float*)C)[(size_t)(rowb + r) * N + col] = v;
                else ((unsigned short*)C)[(size_t)(rowb + r) * N + col] = f2b(v);
            }
        }
    }
}

// ---------------------------------------------------------------------------
// Attention v8 (R5..R10 best, 50.4 us): unchanged.
// ---------------------------------------------------------------------------
#define ATTN_TILE(Kbuf, Vbuf)                                                            \
    do {                                                                                 \
        __builtin_amdgcn_s_setprio(1);                                                   \
        f32x4 sA[4], sB[4];                                                              \
        _Pragma("unroll")                                                                \
        for (int t = 0; t < 4; ++t) {                                                    \
            const short8 kb0 = *(const short8*)&(Kbuf)[(((t * 16 + l16) * 64) + quad * 8) ^ rx];       \
            const short8 kb1 = *(const short8*)&(Kbuf)[(((t * 16 + l16) * 64) + 32 + quad * 8) ^ rx];  \
            f32x4 z = (f32x4){0.f, 0.f, 0.f, 0.f};                                       \
            sA[t] = MFMA16(kb1, qa1, MFMA16(kb0, qa0, z));                               \
            sB[t] = MFMA16(kb1, qb1, MFMA16(kb0, qb0, z));                               \
        }                                                                                \
        short4b vb[4][4];                                                                \
        _Pragma("unroll")                                                                \
        for (int t = 0; t < 4; ++t)                                                      \
            _Pragma("unroll")                                                            \
            for (int n = 0; n < 4; ++n)                                                  \
                vb[t][n] = *(const short4b*)&(Vbuf)[(((n * 16 + l16) * 64) + t * 16 + quad * 4) ^ rx]; \
        _Pragma("unroll")                                                                \
        for (int t = 0; t < 4; ++t) {                                                    \
            float pA[4], pB[4];                                                          \
            _Pragma("unroll")                                                            \
            for (int r = 0; r < 4; ++r) {                                                \
                pA[r] = EXP2(sA[t][r]);                                                  \
                pB[r] = EXP2(sB[t][r]);                                                  \
            }                                                                            \
            union { unsigned u[2]; short4b s; } fa, fb;                                  \
            fa.u[0] = __builtin_amdgcn_perm(f_as_u(pA[1]), f_as_u(pA[0]), 0x07060302u);  \
            fa.u[1] = __builtin_amdgcn_perm(f_as_u(pA[3]), f_as_u(pA[2]), 0x07060302u);  \
            fb.u[0] = __builtin_amdgcn_perm(f_as_u(pB[1]), f_as_u(pB[0]), 0x07060302u);  \
            fb.u[1] = __builtin_amdgcn_perm(f_as_u(pB[3]), f_as_u(pB[2]), 0x07060302u);  \
            _Pragma("unroll")                                                            \
            for (int n = 0; n < 4; ++n) {                                                \
                oA[n] = MFMA16K16(fa.s, vb[t][n], oA[n]);                                \
                oB[n] = MFMA16K16(fb.s, vb[t][n], oB[n]);                                \
            }                                                                            \
            sumA = MFMA16K16(fa.s, ones, sumA);                                          \
            sumB = MFMA16K16(fb.s, ones, sumB);                                          \
        }                                                                                \
        __builtin_amdgcn_s_setprio(0);                                                   \
    } while (0)

__global__ __launch_bounds__(256) void attn_kernel(const unsigned short* __restrict__ qkv,
                                                   const unsigned short* __restrict__ VtG,
                                                   unsigned short* __restrict__ out) {
    __shared__ __align__(16) unsigned short Ks[2][64 * 64];   // [buf][key][dk], swizzled
    __shared__ __align__(16) unsigned short Vs[2][64 * 64];   // [buf][dk][key], swizzled

    // T1: XCD-chunk swizzle (512 blocks, 8 XCDs): each bh fully on one XCD.
    const int l = blockIdx.y * 16 + blockIdx.x;
    const int v = (l & 7) * 64 + (l >> 3);
    const int qt = v & 15, bh = v >> 4;
    const int b = bh >> 4, h = bh & 15;
    const int tid = threadIdx.x, wave = tid >> 6, lane = tid & 63;
    const int quad = lane >> 4, l16 = lane & 15;

    const int qrowA = qt * 128 + wave * 16 + l16;
    const unsigned short* qpA = qkv + (size_t)(b * 2048 + qrowA) * 3072 + h * 64;
    const unsigned short* qpB = qpA + (size_t)64 * 3072;
    const short8 qa0 = *(const short8*)(qpA + quad * 8);
    const short8 qa1 = *(const short8*)(qpA + 32 + quad * 8);
    const short8 qb0 = *(const short8*)(qpB + quad * 8);
    const short8 qb1 = *(const short8*)(qpB + 32 + quad * 8);

    f32x4 oA[4], oB[4], sumA, sumB;
    #pragma unroll
    for (int n = 0; n < 4; n++) { oA[n] = (f32x4){0.f,0.f,0.f,0.f}; oB[n] = (f32x4){0.f,0.f,0.f,0.f}; }
    sumA = (f32x4){0.f,0.f,0.f,0.f};
    sumB = (f32x4){0.f,0.f,0.f,0.f};

    const short4b ones = { (short)0x3F80, (short)0x3F80, (short)0x3F80, (short)0x3F80 };  // bf16 1.0

    // staging geometry: thread covers (srow, scol..scol+15)
    const int srow = tid >> 2;          // 0..63
    const int scol = (tid & 3) * 16;    // 0,16,32,48
    const int sxor = (srow & 7) << 3;   // write-side swizzle (short-index XOR)
    const unsigned short* kg = qkv + (size_t)(b * 2048 + srow) * 3072 + 1024 + h * 64 + scol;
    const unsigned short* vg = VtG + (size_t)(bh * 64 + srow) * 2048 + scol;
    const size_t kstep = (size_t)64 * 3072;
    const int sidx0 = (srow * 64 + scol) ^ sxor;
    const int sidx1 = (srow * 64 + scol + 8) ^ sxor;
    unsigned short* wK0a = &Ks[0][sidx0];  unsigned short* wK1a = &Ks[0][sidx1];
    unsigned short* wV0a = &Vs[0][sidx0];  unsigned short* wV1a = &Vs[0][sidx1];
    unsigned short* wK0b = &Ks[1][sidx0];  unsigned short* wK1b = &Ks[1][sidx1];
    unsigned short* wV0b = &Vs[1][sidx0];  unsigned short* wV1b = &Vs[1][sidx1];

    const int rx = (l16 & 7) << 3;      // read-side swizzle

    // prologue: tile 0 -> regA -> bufA; tile 1 -> regB
    short8 rkA0 = *(const short8*)(kg);
    short8 rkA1 = *(const short8*)(kg + 8);
    short8 rvA0 = *(const short8*)(vg);
    short8 rvA1 = *(const short8*)(vg + 8);
    *(short8*)wK0a = rkA0;  *(short8*)wK1a = rkA1;
    *(short8*)wV0a = rvA0;  *(short8*)wV1a = rvA1;
    short8 rkB0 = *(const short8*)(kg + kstep);
    short8 rkB1 = *(const short8*)(kg + kstep + 8);
    short8 rvB0 = *(const short8*)(vg + 64);
    short8 rvB1 = *(const short8*)(vg + 64 + 8);
    __syncthreads();

    for (int kt = 0; kt < 32; kt += 2) {
        // EVEN: stage regB(tile kt+1)->bufB; issue loads kt+2->regA; compute bufA(kt)
        *(short8*)wK0b = rkB0;  *(short8*)wK1b = rkB1;
        *(short8*)wV0b = rvB0;  *(short8*)wV1b = rvB1;
        if (kt + 2 < 32) {
            rkA0 = *(const short8*)(kg + (kt + 2) * kstep);
            rkA1 = *(const short8*)(kg + (kt + 2) * kstep + 8);
            rvA0 = *(const short8*)(vg + (kt + 2) * 64);
            rvA1 = *(const short8*)(vg + (kt + 2) * 64 + 8);
        }
        ATTN_TILE(Ks[0], Vs[0]);
        __syncthreads();

        // ODD: stage regA(tile kt+2)->bufA; issue loads kt+3->regB; compute bufB(kt+1)
        if (kt + 2 < 32) {
            *(short8*)wK0a = rkA0;  *(short8*)wK1a = rkA1;
            *(short8*)wV0a = rvA0;  *(short8*)wV1a = rvA1;
        }
        if (kt + 3 < 32) {
            rkB0 = *(const short8*)(kg + (kt + 3) * kstep);
            rkB1 = *(const short8*)(kg + (kt + 3) * kstep + 8);
            rvB0 = *(const short8*)(vg + (kt + 3) * 64);
            rvB1 = *(const short8*)(vg + (kt + 3) * 64 + 8);
        }
        ATTN_TILE(Ks[1], Vs[1]);
        __syncthreads();
    }

    float invA[4], invB[4];
    #pragma unroll
    for (int r = 0; r < 4; ++r) { invA[r] = 1.0f / sumA[r]; invB[r] = 1.0f / sumB[r]; }
    #pragma unroll
    for (int n = 0; n < 4; n++)
        #pragma unroll
        for (int r = 0; r < 4; r++) {
            const int row = qt * 128 + wave * 16 + quad * 4 + r;
            out[(size_t)(b * 2048 + row) * 1024 + h * 64 + n * 16 + l16] = f2b(oA[n][r] * invA[r]);
            out[(size_t)(b * 2048 + row + 64) * 1024 + h * 64 + n * 16 + l16] = f2b(oB[n][r] * invB[r]);
        }
}

// ---------------------------------------------------------------------------
extern "C" void kernel_launch(void* const* d_in, const int* in_sizes, int n_in,
                              void* d_out, int out_size, void* d_ws, size_t ws_size,
                              hipStream_t stream) {
    const void* x  = d_in[0];
    const int*  mk = (const int*)d_in[1];
    const void* Wq = d_in[2]; const void* bq = d_in[3];
    const void* Wk = d_in[4]; const void* bk = d_in[5];
    const void* Wv = d_in[6]; const void* bv = d_in[7];
    const void* Wo = d_in[8]; const void* bo = d_in[9];

    char* wsb = (char*)d_ws;
    int* flag = (int*)wsb;                                   // 64B header
    unsigned short* W0 = (unsigned short*)(wsb + 64);

    const size_t M1 = 1024u * 1024u;
    const size_t M4 = 4096u * 1024u;
    unsigned short* xb  = W0;                                // 4M elems (now just abf)
    unsigned short* WT  = xb + M4;                           // 3M: Wq^T|Wk^T|Wv^T
    unsigned short* WoT = WT + 3 * M1;                       // 1M (contiguous after WT)
    unsigned short* b3  = WoT + M1;                          // 3072 (pad 4096)
    unsigned short* bob = b3 + 4096;                         // 1024
    unsigned short* qkv = bob + 1024;                        // 12M (V third unused)
    unsigned short* VtG = qkv + (size_t)4096 * 3072;         // 4M  (total ~48MB)
    unsigned short* abf = xb;                                // attn output buffer

    detect_dtype<<<1, 256, 0, stream>>>((const unsigned short*)x, flag);

    convtrans_k<<<dim3(16, 16, 5), 256, 0, stream>>>(Wq, Wk, Wv, Wo, bq, bk, bv, bo,
                                                     WT, b3, bob, flag);

    gemm_qkv<<<dim3(24, 32), 256, 0, stream>>>(x, WT, b3, qkv, VtG, mk, flag, 1024);
    attn_kernel<<<dim3(16, 32), 256, 0, stream>>>(qkv, VtG, abf);
    gemm64_bias_relu<<<dim3(8, 64), 256, 0, stream>>>(abf, WoT, bob, d_out, flag, 1024, 1024);
}

// Round 12
// 196.055 us; speedup vs baseline: 1.1563x; 1.1563x over previous
//
#include <hip/hip_runtime.h>
#include <stdint.h>

typedef __attribute__((ext_vector_type(8))) short short8;   // 8 bf16 (4 VGPRs)
typedef __attribute__((ext_vector_type(4))) short short4b;  // 4 bf16 (2 VGPRs)
typedef __attribute__((ext_vector_type(4))) float f32x4;    // MFMA acc

#define MFMA16(a, b, c) __builtin_amdgcn_mfma_f32_16x16x32_bf16((a), (b), (c), 0, 0, 0)

#if defined(__HIP_DEVICE_COMPILE__)
  #if __has_builtin(__builtin_amdgcn_mfma_f32_16x16x16bf16_1k)
    #define MFMA16K16(a, b, c) __builtin_amdgcn_mfma_f32_16x16x16bf16_1k((a), (b), (c), 0, 0, 0)
  #else
    #define MFMA16K16(a, b, c) __builtin_amdgcn_mfma_f32_16x16x16_bf16((a), (b), (c), 0, 0, 0)
  #endif
  #if __has_builtin(__builtin_amdgcn_exp2f)
    #define EXP2(x) __builtin_amdgcn_exp2f(x)   // raw v_exp_f32: 1 instr, exact for our S>=0 range
  #else
    #define EXP2(x) exp2f(x)
  #endif
#else
  #define MFMA16K16(a, b, c) (c)
  #define EXP2(x) exp2f(x)
#endif

#define SCL_F (0.125f * 1.44269504f)   // dk^-0.5 folded with log2(e)

__device__ __forceinline__ float b2f(unsigned short u) {
    union { unsigned u; float f; } c; c.u = ((unsigned)u) << 16; return c.f;
}
__device__ __forceinline__ unsigned short f2b(float f) {
    union { float f; unsigned u; } c; c.f = f;
    unsigned r = c.u + 0x7FFF + ((c.u >> 16) & 1);   // round-to-nearest-even
    return (unsigned short)(r >> 16);
}
__device__ __forceinline__ unsigned f_as_u(float f) {
    union { float f; unsigned u; } c; c.f = f; return c.u;
}

// async global->LDS, 16B per lane; LDS dest = wave-uniform base + lane*16.
__device__ __forceinline__ void g2lds16(const unsigned short* g, unsigned lds_byte_off) {
    __builtin_amdgcn_global_load_lds(
        (const __attribute__((address_space(1))) void*)(uintptr_t)g,
        (__attribute__((address_space(3))) void*)(uintptr_t)lds_byte_off,
        16, 0, 0);
}

// ---------------------------------------------------------------------------
// Dtype canary (proven): flag=1 => f32 inputs, 0 => bf16.
// ---------------------------------------------------------------------------
__global__ void detect_dtype(const unsigned short* __restrict__ x, int* __restrict__ flag) {
    __shared__ int cnt;
    if (threadIdx.x == 0) cnt = 0;
    __syncthreads();
    int insane = 0;
    #pragma unroll
    for (int j = 0; j < 4; ++j) {
        unsigned short u = x[threadIdx.x * 4 + j];
        int e = (u >> 7) & 0xFF;
        if ((e >= 1 && e <= 90) || e >= 165) insane++;
    }
    atomicAdd(&cnt, insane);
    __syncthreads();
    if (threadIdx.x == 0) *flag = (cnt > 128) ? 1 : 0;
}

// ---------------------------------------------------------------------------
// Fused convert+transpose for 4 weights (z=0..3), biases (z=4), and the
// x f32->bf16 conversion (z=5..12). Wq (z=0) and bq (w=0) are SCALED by
// SCL_F. (R11's fused-into-GEMM conversion regressed: the separate streaming
// pass reads x ONCE; the GEMM tiling multiplied f32 traffic 2x. Reverted.)
// ---------------------------------------------------------------------------
__global__ __launch_bounds__(256) void convtrans_k(const void* __restrict__ s0, const void* __restrict__ s1,
                                                   const void* __restrict__ s2, const void* __restrict__ s3,
                                                   const void* __restrict__ b0, const void* __restrict__ b1,
                                                   const void* __restrict__ b2, const void* __restrict__ b3s,
                                                   const void* __restrict__ xsrc,
                                                   unsigned short* __restrict__ xdst,
                                                   unsigned short* __restrict__ dstBase,
                                                   unsigned short* __restrict__ dstB3,
                                                   unsigned short* __restrict__ dstBo,
                                                   const int* __restrict__ flag) {
    const int z = blockIdx.z;
    if (z >= 5) {           // x conversion: 8 slices x 256 blocks x 256 thr x 8 elems
        if (!*flag) return;
        const int slice = z - 5;
        const size_t i0 = (size_t)slice * 524288 + (blockIdx.y * 16 + blockIdx.x) * 2048 + threadIdx.x * 8;
        const float* s = (const float*)xsrc;
        float4 f0 = *(const float4*)&s[i0];
        float4 f1 = *(const float4*)&s[i0 + 4];
        union { short8 v; unsigned short u[8]; } o;
        o.u[0] = f2b(f0.x); o.u[1] = f2b(f0.y); o.u[2] = f2b(f0.z); o.u[3] = f2b(f0.w);
        o.u[4] = f2b(f1.x); o.u[5] = f2b(f1.y); o.u[6] = f2b(f1.z); o.u[7] = f2b(f1.w);
        *(short8*)&xdst[i0] = o.v;
        return;
    }
    if (z == 4) {           // biases (bq scaled by SCL_F)
        if (blockIdx.y != 0 || blockIdx.x >= 4) return;
        const int w = blockIdx.x;
        const void* src = (w == 0) ? b0 : (w == 1) ? b1 : (w == 2) ? b2 : b3s;
        const float bscl = (w == 0) ? SCL_F : 1.0f;
        #pragma unroll
        for (int j = 0; j < 4; ++j) {
            const int i = threadIdx.x * 4 + j;
            float fv = (*flag) ? ((const float*)src)[i] : b2f(((const unsigned short*)src)[i]);
            unsigned short v = f2b(fv * bscl);
            if (w < 3) dstB3[w * 1024 + i] = v;
            else dstBo[i] = v;
        }
        return;
    }
    __shared__ __align__(16) unsigned short tile[64 * 72];
    const void* src = (z == 0) ? s0 : (z == 1) ? s1 : (z == 2) ? s2 : s3;
    unsigned short* dst = dstBase + (size_t)z * 1024 * 1024;
    const float wscl = (z == 0) ? SCL_F : 1.0f;
    const int tid = threadIdx.x;
    const int r0 = blockIdx.y * 64, c0 = blockIdx.x * 64;
    const int rb = tid >> 3, c = (tid & 7) * 8;
    if (*flag) {
        const float* s = (const float*)src;
        #pragma unroll
        for (int it = 0; it < 2; ++it) {
            int rr = it * 32 + rb;
            float4 f0 = *(const float4*)&s[(size_t)(r0 + rr) * 1024 + c0 + c];
            float4 f1 = *(const float4*)&s[(size_t)(r0 + rr) * 1024 + c0 + c + 4];
            unsigned short* t = &tile[rr * 72 + c];
            t[0] = f2b(f0.x * wscl); t[1] = f2b(f0.y * wscl); t[2] = f2b(f0.z * wscl); t[3] = f2b(f0.w * wscl);
            t[4] = f2b(f1.x * wscl); t[5] = f2b(f1.y * wscl); t[6] = f2b(f1.z * wscl); t[7] = f2b(f1.w * wscl);
        }
    } else if (z == 0) {
        const unsigned short* s = (const unsigned short*)src;
        #pragma unroll
        for (int it = 0; it < 2; ++it) {
            int rr = it * 32 + rb;
            union { short8 v; unsigned short u[8]; } in;
            in.v = *(const short8*)&s[(size_t)(r0 + rr) * 1024 + c0 + c];
            unsigned short* t = &tile[rr * 72 + c];
            #pragma unroll
            for (int j = 0; j < 8; ++j) t[j] = f2b(b2f(in.u[j]) * SCL_F);
        }
    } else {
        const unsigned short* s = (const unsigned short*)src;
        #pragma unroll
        for (int it = 0; it < 2; ++it) {
            int rr = it * 32 + rb;
            *(short8*)&tile[rr * 72 + c] = *(const short8*)&s[(size_t)(r0 + rr) * 1024 + c0 + c];
        }
    }
    __syncthreads();
    #pragma unroll
    for (int it = 0; it < 2; ++it) {
        int n = it * 32 + rb, k8 = c;
        union { short8 s; unsigned short u[8]; } tmp;
        #pragma unroll
        for (int j = 0; j < 8; ++j) tmp.u[j] = tile[(k8 + j) * 72 + n];
        *(short8*)&dst[(size_t)(c0 + n) * 1024 + r0 + k8] = tmp.s;
    }
}

// ---------------------------------------------------------------------------
// QKV GEMM: BM=BN=128, BK=32, 3-deep counted-vmcnt pipeline + T2 swizzle
// (R9) + LDS-bounce epilogue with fused mask (R8). Best-measured config.
// ---------------------------------------------------------------------------
__global__ __launch_bounds__(256) void gemm_qkv(const unsigned short* __restrict__ A,
                                                const void* __restrict__ Araw,
                                                const unsigned short* __restrict__ BT,
                                                const unsigned short* __restrict__ bias,
                                                unsigned short* __restrict__ qkv,
                                                unsigned short* __restrict__ VtG,
                                                const int* __restrict__ mask,
                                                const int* __restrict__ flag,
                                                int K) {
    __shared__ __align__(16) unsigned short smem[24576];   // 48KB; epilogue reuses
    const int tid = threadIdx.x;
    const int wave = tid >> 6, lane = tid & 63;
    const int quad = lane >> 4, l16 = lane & 15;
    const int wm = wave >> 1, wn = wave & 1;
    const int m0 = blockIdx.y * 128, n0 = blockIdx.x * 128;

    const unsigned short* Ause = (Araw != nullptr && *flag == 0) ? (const unsigned short*)Araw : A;

    f32x4 acc[4][4];
    #pragma unroll
    for (int i = 0; i < 4; i++)
        #pragma unroll
        for (int j = 0; j < 4; j++) acc[i][j] = (f32x4){0.f, 0.f, 0.f, 0.f};

    // T2 staging geometry: lane -> (row_local, col8) pre-swizzled
    const int r2 = lane >> 3, sl = lane & 7;
    const int sp = sl ^ r2;                    // s' (r2 in 0..7)
    const int rowl = r2 * 2 + (sp >> 2);       // 0..15
    const int col8 = (sp & 3) * 8;
    const unsigned short* gA0 = Ause + (size_t)(m0 + wave * 32 + rowl) * K + col8;
    const unsigned short* gA1 = gA0 + (size_t)16 * K;
    const unsigned short* gB0 = BT + (size_t)(n0 + wave * 32 + rowl) * K + col8;
    const unsigned short* gB1 = gB0 + (size_t)16 * K;

    const unsigned sA = (unsigned)(uintptr_t)&smem[0];
    const unsigned sB = sA + 24576;                         // bytes
    unsigned lA0 = sA + wave * 2048;
    unsigned lA1 = sA + 8192 + wave * 2048;
    unsigned lA2 = sA + 16384 + wave * 2048;
    unsigned lB0 = sB + wave * 2048;
    unsigned lB1 = sB + 8192 + wave * 2048;
    unsigned lB2 = sB + 16384 + wave * 2048;
    const unsigned short* pA0 = &smem[0];
    const unsigned short* pA1 = &smem[4096];
    const unsigned short* pA2 = &smem[8192];
    const unsigned short* pB0 = &smem[12288];
    const unsigned short* pB1 = &smem[16384];
    const unsigned short* pB2 = &smem[20480];

    // T2 read geometry (swizzled fragment offsets)
    const int swz = (((l16 & 1) << 2) | quad) ^ (l16 >> 1);
    const int hp  = l16 >> 1;                  // half-pair index within 16 rows

    g2lds16(gA0, lA0); g2lds16(gA1, lA0 + 1024);
    g2lds16(gB0, lB0); g2lds16(gB1, lB0 + 1024);
    if (32 < K) {
        g2lds16(gA0 + 32, lA1); g2lds16(gA1 + 32, lA1 + 1024);
        g2lds16(gB0 + 32, lB1); g2lds16(gB1 + 32, lB1 + 1024);
    }
    if (64 < K) {
        g2lds16(gA0 + 64, lA2); g2lds16(gA1 + 64, lA2 + 1024);
        g2lds16(gB0 + 64, lB2); g2lds16(gB1 + 64, lB2 + 1024);
    }

    for (int k0 = 0; k0 < K; k0 += 32) {
        if (k0 + 64 < K)       asm volatile("s_waitcnt vmcnt(8)" ::: "memory");
        else if (k0 + 32 < K)  asm volatile("s_waitcnt vmcnt(4)" ::: "memory");
        else                   asm volatile("s_waitcnt vmcnt(0)" ::: "memory");
        __builtin_amdgcn_s_barrier();

        short8 af[4], bf[4];
        #pragma unroll
        for (int i = 0; i < 4; i++) af[i] = *(const short8*)&pA0[(wm * 32 + i * 8 + hp) * 64 + swz * 8];
        #pragma unroll
        for (int j = 0; j < 4; j++) bf[j] = *(const short8*)&pB0[(wn * 32 + j * 8 + hp) * 64 + swz * 8];
        #pragma unroll
        for (int i = 0; i < 4; i++)
            #pragma unroll
            for (int j = 0; j < 4; j++)
                acc[i][j] = MFMA16(af[i], bf[j], acc[i][j]);

        __builtin_amdgcn_s_barrier();

        if (k0 + 96 < K) {
            g2lds16(gA0 + k0 + 96, lA0); g2lds16(gA1 + k0 + 96, lA0 + 1024);
            g2lds16(gB0 + k0 + 96, lB0); g2lds16(gB1 + k0 + 96, lB0 + 1024);
        }
        unsigned tu;
        tu = lA0; lA0 = lA1; lA1 = lA2; lA2 = tu;
        tu = lB0; lB0 = lB1; lB1 = lB2; lB2 = tu;
        const unsigned short* tp;
        tp = pA0; pA0 = pA1; pA1 = pA2; pA2 = tp;
        tp = pB0; pB0 = pB1; pB1 = pB2; pB2 = tp;
    }
    // last iter's second barrier has run: staging LDS free for epilogue reuse.

    unsigned short* epi = &smem[0];                 // 128 x (132) tile, 33.8KB
    if (n0 >= 2048) {
        // V: store transposed into LDS: epi[col_local*132 + row_local]
        #pragma unroll
        for (int j = 0; j < 4; j++) {
            const int cl = wn * 64 + j * 16 + l16;
            const float bj = b2f(bias[n0 + cl]);
            #pragma unroll
            for (int i = 0; i < 4; i++) {
                const int rl = wm * 64 + i * 16 + quad * 4;
                #pragma unroll
                for (int r = 0; r < 4; r++) {
                    float v = acc[i][j][r] + bj;
                    v = v > 0.f ? v : 0.f;
                    epi[cl * 132 + rl + r] = f2b(v);
                }
            }
        }
        __syncthreads();
        // coalesced store: thread t -> col t>>1, half (t&1)*64; 128B contiguous
        const int cl = tid >> 1, half = (tid & 1) * 64;
        const int colg = n0 + cl;
        const int h  = (colg - 2048) >> 6;
        const int dk = (colg - 2048) & 63;
        const int bb = m0 >> 11;
        unsigned short* dst = &VtG[((size_t)(bb * 16 + h) * 64 + dk) * 2048 + (m0 & 2047) + half];
        const unsigned short* src = &epi[cl * 132 + half];
        #pragma unroll
        for (int k = 0; k < 8; k++) *(short8*)&dst[k * 8] = *(const short8*)&src[k * 8];
    } else {
        // Q/K: store row-major into LDS: epi[row_local*132 + col_local]
        #pragma unroll
        for (int j = 0; j < 4; j++) {
            const int cl = wn * 64 + j * 16 + l16;
            const float bj = b2f(bias[n0 + cl]);
            #pragma unroll
            for (int i = 0; i < 4; i++) {
                const int rl = wm * 64 + i * 16 + quad * 4;
                #pragma unroll
                for (int r = 0; r < 4; r++) {
                    float v = acc[i][j][r] + bj;
                    v = v > 0.f ? v : 0.f;
                    epi[(rl + r) * 132 + cl] = f2b(v);
                }
            }
        }
        __syncthreads();
        const int row = tid >> 1, half = (tid & 1) * 64;
        const int rowg = m0 + row;
        const int mz = (n0 >= 1024) && mask[rowg];          // K third + masked row
        unsigned short* dst = &qkv[(size_t)rowg * 3072 + n0 + half];
        const unsigned short* src = &epi[row * 132 + half];
        const short8 zero = {0, 0, 0, 0, 0, 0, 0, 0};
        #pragma unroll
        for (int k = 0; k < 8; k++) *(short8*)&dst[k * 8] = mz ? zero : *(const short8*)&src[k * 8];
    }
}

// ---------------------------------------------------------------------------
// OUT projection: BM=64 x BN=128, BK=32, 3-deep pipeline + T2 swizzle (R9
// form, best-total config). relu(A@BT^T+bias); f32 out when flag.
// ---------------------------------------------------------------------------
__global__ __launch_bounds__(256) void gemm64_bias_relu(const unsigned short* __restrict__ A,
                                                        const unsigned short* __restrict__ BT,
                                                        const unsigned short* __restrict__ bias,
                                                        void* __restrict__ C,
                                                        const int* __restrict__ flag,
                                                        int N, int K) {
    __shared__ __align__(16) unsigned short As[3][64 * 32];
    __shared__ __align__(16) unsigned short Bs[3][128 * 32];
    const int tid = threadIdx.x;
    const int wave = tid >> 6, lane = tid & 63;
    const int quad = lane >> 4, l16 = lane & 15;
    const int wm = wave >> 1, wn = wave & 1;      // wave tile: 32 rows x 64 cols
    const int m0 = blockIdx.y * 64, n0 = blockIdx.x * 128;

    f32x4 acc[2][4];
    #pragma unroll
    for (int i = 0; i < 2; i++)
        #pragma unroll
        for (int j = 0; j < 4; j++) acc[i][j] = (f32x4){0.f, 0.f, 0.f, 0.f};

    // T2 staging geometry
    const int r2 = lane >> 3, sl = lane & 7;
    const int sp = sl ^ r2;
    const int rowl = r2 * 2 + (sp >> 2);
    const int col8 = (sp & 3) * 8;
    const unsigned short* gA0 = A + (size_t)(m0 + wave * 16 + rowl) * K + col8;
    const unsigned short* gB0 = BT + (size_t)(n0 + wave * 32 + rowl) * K + col8;
    const unsigned short* gB1 = gB0 + (size_t)16 * K;

    unsigned lA0 = (unsigned)(uintptr_t)&As[0][0] + wave * 1024;
    unsigned lA1 = (unsigned)(uintptr_t)&As[1][0] + wave * 1024;
    unsigned lA2 = (unsigned)(uintptr_t)&As[2][0] + wave * 1024;
    unsigned lB0 = (unsigned)(uintptr_t)&Bs[0][0] + wave * 2048;
    unsigned lB1 = (unsigned)(uintptr_t)&Bs[1][0] + wave * 2048;
    unsigned lB2 = (unsigned)(uintptr_t)&Bs[2][0] + wave * 2048;
    const unsigned short* pA0 = &As[0][0];
    const unsigned short* pA1 = &As[1][0];
    const unsigned short* pA2 = &As[2][0];
    const unsigned short* pB0 = &Bs[0][0];
    const unsigned short* pB1 = &Bs[1][0];
    const unsigned short* pB2 = &Bs[2][0];

    const int swz = (((l16 & 1) << 2) | quad) ^ (l16 >> 1);
    const int hp  = l16 >> 1;

    g2lds16(gA0, lA0);
    g2lds16(gB0, lB0); g2lds16(gB1, lB0 + 1024);
    if (32 < K) {
        g2lds16(gA0 + 32, lA1);
        g2lds16(gB0 + 32, lB1); g2lds16(gB1 + 32, lB1 + 1024);
    }
    if (64 < K) {
        g2lds16(gA0 + 64, lA2);
        g2lds16(gB0 + 64, lB2); g2lds16(gB1 + 64, lB2 + 1024);
    }

    for (int k0 = 0; k0 < K; k0 += 32) {
        if (k0 + 64 < K)       asm volatile("s_waitcnt vmcnt(6)" ::: "memory");
        else if (k0 + 32 < K)  asm volatile("s_waitcnt vmcnt(3)" ::: "memory");
        else                   asm volatile("s_waitcnt vmcnt(0)" ::: "memory");
        __builtin_amdgcn_s_barrier();

        short8 af[2], bf[4];
        #pragma unroll
        for (int i = 0; i < 2; i++) af[i] = *(const short8*)&pA0[(wm * 16 + i * 8 + hp) * 64 + swz * 8];
        #pragma unroll
        for (int j = 0; j < 4; j++) bf[j] = *(const short8*)&pB0[(wn * 32 + j * 8 + hp) * 64 + swz * 8];
        #pragma unroll
        for (int i = 0; i < 2; i++)
            #pragma unroll
            for (int j = 0; j < 4; j++)
                acc[i][j] = MFMA16(af[i], bf[j], acc[i][j]);

        __builtin_amdgcn_s_barrier();

        if (k0 + 96 < K) {
            g2lds16(gA0 + k0 + 96, lA0);
            g2lds16(gB0 + k0 + 96, lB0); g2lds16(gB1 + k0 + 96, lB0 + 1024);
        }
        unsigned tu;
        tu = lA0; lA0 = lA1; lA1 = lA2; lA2 = tu;
        tu = lB0; lB0 = lB1; lB1 = lB2; lB2 = tu;
        const unsigned short* tp;
        tp = pA0; pA0 = pA1; pA1 = pA2; pA2 = tp;
        tp = pB0; pB0 = pB1; pB1 = pB2; pB2 = tp;
    }

    const int f32out = (*flag != 0);
    #pragma unroll
    for (int j = 0; j < 4; j++) {
        const int col = n0 + wn * 64 + j * 16 + l16;
        const float bj = b2f(bias[col]);
        #pragma unroll
        for (int i = 0; i < 2; i++) {
            const int rowb = m0 + wm * 32 + i * 16 + quad * 4;
            #pragma unroll
            for (int r = 0; r < 4; r++) {
                float v = acc[i][j][r] + bj;
                v = v > 0.f ? v : 0.f;
                if (f32out) ((float*)C)[(size_t)(rowb + r) * N + col] = v;
                else ((unsigned short*)C)[(size_t)(rowb + r) * N + col] = f2b(v);
            }
        }
    }
}

// ---------------------------------------------------------------------------
// Attention v8 (R5..R10 best, 50.4 us): unchanged.
// ---------------------------------------------------------------------------
#define ATTN_TILE(Kbuf, Vbuf)                                                            \
    do {                                                                                 \
        __builtin_amdgcn_s_setprio(1);                                                   \
        f32x4 sA[4], sB[4];                                                              \
        _Pragma("unroll")                                                                \
        for (int t = 0; t < 4; ++t) {                                                    \
            const short8 kb0 = *(const short8*)&(Kbuf)[(((t * 16 + l16) * 64) + quad * 8) ^ rx];       \
            const short8 kb1 = *(const short8*)&(Kbuf)[(((t * 16 + l16) * 64) + 32 + quad * 8) ^ rx];  \
            f32x4 z = (f32x4){0.f, 0.f, 0.f, 0.f};                                       \
            sA[t] = MFMA16(kb1, qa1, MFMA16(kb0, qa0, z));                               \
            sB[t] = MFMA16(kb1, qb1, MFMA16(kb0, qb0, z));                               \
        }                                                                                \
        short4b vb[4][4];                                                                \
        _Pragma("unroll")                                                                \
        for (int t = 0; t < 4; ++t)                                                      \
            _Pragma("unroll")                                                            \
            for (int n = 0; n < 4; ++n)                                                  \
                vb[t][n] = *(const short4b*)&(Vbuf)[(((n * 16 + l16) * 64) + t * 16 + quad * 4) ^ rx]; \
        _Pragma("unroll")                                                                \
        for (int t = 0; t < 4; ++t) {                                                    \
            float pA[4], pB[4];                                                          \
            _Pragma("unroll")                                                            \
            for (int r = 0; r < 4; ++r) {                                                \
                pA[r] = EXP2(sA[t][r]);                                                  \
                pB[r] = EXP2(sB[t][r]);                                                  \
            }                                                                            \
            union { unsigned u[2]; short4b s; } fa, fb;                                  \
            fa.u[0] = __builtin_amdgcn_perm(f_as_u(pA[1]), f_as_u(pA[0]), 0x07060302u);  \
            fa.u[1] = __builtin_amdgcn_perm(f_as_u(pA[3]), f_as_u(pA[2]), 0x07060302u);  \
            fb.u[0] = __builtin_amdgcn_perm(f_as_u(pB[1]), f_as_u(pB[0]), 0x07060302u);  \
            fb.u[1] = __builtin_amdgcn_perm(f_as_u(pB[3]), f_as_u(pB[2]), 0x07060302u);  \
            _Pragma("unroll")                                                            \
            for (int n = 0; n < 4; ++n) {                                                \
                oA[n] = MFMA16K16(fa.s, vb[t][n], oA[n]);                                \
                oB[n] = MFMA16K16(fb.s, vb[t][n], oB[n]);                                \
            }                                                                            \
            sumA = MFMA16K16(fa.s, ones, sumA);                                          \
            sumB = MFMA16K16(fb.s, ones, sumB);                                          \
        }                                                                                \
        __builtin_amdgcn_s_setprio(0);                                                   \
    } while (0)

__global__ __launch_bounds__(256) void attn_kernel(const unsigned short* __restrict__ qkv,
                                                   const unsigned short* __restrict__ VtG,
                                                   unsigned short* __restrict__ out) {
    __shared__ __align__(16) unsigned short Ks[2][64 * 64];   // [buf][key][dk], swizzled
    __shared__ __align__(16) unsigned short Vs[2][64 * 64];   // [buf][dk][key], swizzled

    // T1: XCD-chunk swizzle (512 blocks, 8 XCDs): each bh fully on one XCD.
    const int l = blockIdx.y * 16 + blockIdx.x;
    const int v = (l & 7) * 64 + (l >> 3);
    const int qt = v & 15, bh = v >> 4;
    const int b = bh >> 4, h = bh & 15;
    const int tid = threadIdx.x, wave = tid >> 6, lane = tid & 63;
    const int quad = lane >> 4, l16 = lane & 15;

    const int qrowA = qt * 128 + wave * 16 + l16;
    const unsigned short* qpA = qkv + (size_t)(b * 2048 + qrowA) * 3072 + h * 64;
    const unsigned short* qpB = qpA + (size_t)64 * 3072;
    const short8 qa0 = *(const short8*)(qpA + quad * 8);
    const short8 qa1 = *(const short8*)(qpA + 32 + quad * 8);
    const short8 qb0 = *(const short8*)(qpB + quad * 8);
    const short8 qb1 = *(const short8*)(qpB + 32 + quad * 8);

    f32x4 oA[4], oB[4], sumA, sumB;
    #pragma unroll
    for (int n = 0; n < 4; n++) { oA[n] = (f32x4){0.f,0.f,0.f,0.f}; oB[n] = (f32x4){0.f,0.f,0.f,0.f}; }
    sumA = (f32x4){0.f,0.f,0.f,0.f};
    sumB = (f32x4){0.f,0.f,0.f,0.f};

    const short4b ones = { (short)0x3F80, (short)0x3F80, (short)0x3F80, (short)0x3F80 };  // bf16 1.0

    // staging geometry: thread covers (srow, scol..scol+15)
    const int srow = tid >> 2;          // 0..63
    const int scol = (tid & 3) * 16;    // 0,16,32,48
    const int sxor = (srow & 7) << 3;   // write-side swizzle (short-index XOR)
    const unsigned short* kg = qkv + (size_t)(b * 2048 + srow) * 3072 + 1024 + h * 64 + scol;
    const unsigned short* vg = VtG + (size_t)(bh * 64 + srow) * 2048 + scol;
    const size_t kstep = (size_t)64 * 3072;
    const int sidx0 = (srow * 64 + scol) ^ sxor;
    const int sidx1 = (srow * 64 + scol + 8) ^ sxor;
    unsigned short* wK0a = &Ks[0][sidx0];  unsigned short* wK1a = &Ks[0][sidx1];
    unsigned short* wV0a = &Vs[0][sidx0];  unsigned short* wV1a = &Vs[0][sidx1];
    unsigned short* wK0b = &Ks[1][sidx0];  unsigned short* wK1b = &Ks[1][sidx1];
    unsigned short* wV0b = &Vs[1][sidx0];  unsigned short* wV1b = &Vs[1][sidx1];

    const int rx = (l16 & 7) << 3;      // read-side swizzle

    // prologue: tile 0 -> regA -> bufA; tile 1 -> regB
    short8 rkA0 = *(const short8*)(kg);
    short8 rkA1 = *(const short8*)(kg + 8);
    short8 rvA0 = *(const short8*)(vg);
    short8 rvA1 = *(const short8*)(vg + 8);
    *(short8*)wK0a = rkA0;  *(short8*)wK1a = rkA1;
    *(short8*)wV0a = rvA0;  *(short8*)wV1a = rvA1;
    short8 rkB0 = *(const short8*)(kg + kstep);
    short8 rkB1 = *(const short8*)(kg + kstep + 8);
    short8 rvB0 = *(const short8*)(vg + 64);
    short8 rvB1 = *(const short8*)(vg + 64 + 8);
    __syncthreads();

    for (int kt = 0; kt < 32; kt += 2) {
        // EVEN: stage regB(tile kt+1)->bufB; issue loads kt+2->regA; compute bufA(kt)
        *(short8*)wK0b = rkB0;  *(short8*)wK1b = rkB1;
        *(short8*)wV0b = rvB0;  *(short8*)wV1b = rvB1;
        if (kt + 2 < 32) {
            rkA0 = *(const short8*)(kg + (kt + 2) * kstep);
            rkA1 = *(const short8*)(kg + (kt + 2) * kstep + 8);
            rvA0 = *(const short8*)(vg + (kt + 2) * 64);
            rvA1 = *(const short8*)(vg + (kt + 2) * 64 + 8);
        }
        ATTN_TILE(Ks[0], Vs[0]);
        __syncthreads();

        // ODD: stage regA(tile kt+2)->bufA; issue loads kt+3->regB; compute bufB(kt+1)
        if (kt + 2 < 32) {
            *(short8*)wK0a = rkA0;  *(short8*)wK1a = rkA1;
            *(short8*)wV0a = rvA0;  *(short8*)wV1a = rvA1;
        }
        if (kt + 3 < 32) {
            rkB0 = *(const short8*)(kg + (kt + 3) * kstep);
            rkB1 = *(const short8*)(kg + (kt + 3) * kstep + 8);
            rvB0 = *(const short8*)(vg + (kt + 3) * 64);
            rvB1 = *(const short8*)(vg + (kt + 3) * 64 + 8);
        }
        ATTN_TILE(Ks[1], Vs[1]);
        __syncthreads();
    }

    float invA[4], invB[4];
    #pragma unroll
    for (int r = 0; r < 4; ++r) { invA[r] = 1.0f / sumA[r]; invB[r] = 1.0f / sumB[r]; }
    #pragma unroll
    for (int n = 0; n < 4; n++)
        #pragma unroll
        for (int r = 0; r < 4; r++) {
            const int row = qt * 128 + wave * 16 + quad * 4 + r;
            out[(size_t)(b * 2048 + row) * 1024 + h * 64 + n * 16 + l16] = f2b(oA[n][r] * invA[r]);
            out[(size_t)(b * 2048 + row + 64) * 1024 + h * 64 + n * 16 + l16] = f2b(oB[n][r] * invB[r]);
        }
}

// ---------------------------------------------------------------------------
extern "C" void kernel_launch(void* const* d_in, const int* in_sizes, int n_in,
                              void* d_out, int out_size, void* d_ws, size_t ws_size,
                              hipStream_t stream) {
    const void* x  = d_in[0];
    const int*  mk = (const int*)d_in[1];
    const void* Wq = d_in[2]; const void* bq = d_in[3];
    const void* Wk = d_in[4]; const void* bk = d_in[5];
    const void* Wv = d_in[6]; const void* bv = d_in[7];
    const void* Wo = d_in[8]; const void* bo = d_in[9];

    char* wsb = (char*)d_ws;
    int* flag = (int*)wsb;                                   // 64B header
    unsigned short* W0 = (unsigned short*)(wsb + 64);

    const size_t M1 = 1024u * 1024u;
    const size_t M4 = 4096u * 1024u;
    unsigned short* xb  = W0;                                // 4M elems (reused as abf)
    unsigned short* WT  = xb + M4;                           // 3M: Wq^T|Wk^T|Wv^T
    unsigned short* WoT = WT + 3 * M1;                       // 1M (contiguous after WT)
    unsigned short* b3  = WoT + M1;                          // 3072 (pad 4096)
    unsigned short* bob = b3 + 4096;                         // 1024
    unsigned short* qkv = bob + 1024;                        // 12M (V third unused)
    unsigned short* VtG = qkv + (size_t)4096 * 3072;         // 4M  (total ~48MB)
    unsigned short* abf = xb;                                // alias: x dead after QKV GEMM

    detect_dtype<<<1, 256, 0, stream>>>((const unsigned short*)x, flag);

    convtrans_k<<<dim3(16, 16, 13), 256, 0, stream>>>(Wq, Wk, Wv, Wo, bq, bk, bv, bo,
                                                      x, xb, WT, b3, bob, flag);

    gemm_qkv<<<dim3(24, 32), 256, 0, stream>>>(xb, x, WT, b3, qkv, VtG, mk, flag, 1024);
    attn_kernel<<<dim3(16, 32), 256, 0, stream>>>(qkv, VtG, abf);
    gemm64_bias_relu<<<dim3(8, 64), 256, 0, stream>>>(abf, WoT, bob, d_out, flag, 1024, 1024);
}